// Round 17
// baseline (194.647 us; speedup 1.0000x reference)
//
#include <hip/hip_runtime.h>

#define NN 4096
#define DD 512
#define HH 8
#define FF 64
#define LRELU_ALPHA 0.2f
#define SP 72   // LDS row stride in bf16 elems

typedef __attribute__((ext_vector_type(8))) short bf16x8;
typedef __attribute__((ext_vector_type(4))) float f32x4;

__device__ __forceinline__ float f4c(const float4& v, int k) {
    return k == 0 ? v.x : (k == 1 ? v.y : (k == 2 ? v.z : v.w));
}
__device__ __forceinline__ void f4s(float4& v, int k, float x) {
    if (k == 0) v.x = x; else if (k == 1) v.y = x; else if (k == 2) v.z = x; else v.w = x;
}
__device__ __forceinline__ unsigned short f2bf(float x) {   // RNE float->bf16
    unsigned u = __float_as_uint(x);
    return (unsigned short)((u + 0x7fffu + ((u >> 16) & 1u)) >> 16);
}
__device__ __forceinline__ float bf2f(unsigned short h) {
    return __uint_as_float(((unsigned)h) << 16);
}
// monotone float<->uint key for atomicMax on arbitrary-sign floats
__device__ __forceinline__ unsigned fkey(float x) {
    unsigned u = __float_as_uint(x);
    return (u & 0x80000000u) ? ~u : (u | 0x80000000u);
}
__device__ __forceinline__ float funkey(unsigned k) {
    unsigned u = (k & 0x80000000u) ? (k ^ 0x80000000u) : ~k;
    return __uint_as_float(u);
}
// CK-style barrier: drain LDS counts only; in-flight global->register loads survive.
__device__ __forceinline__ void sync_lds() {
    asm volatile("s_waitcnt lgkmcnt(0)\n\ts_barrier" ::: "memory");
}

// ================= Kernel 1: fused prep =================
__global__ __launch_bounds__(256) void k_prep(const int* __restrict__ adj,
                                              const float* __restrict__ W,
                                              unsigned* __restrict__ adjw,
                                              unsigned short* __restrict__ wt_hi,
                                              unsigned short* __restrict__ wt_lo,
                                              unsigned* __restrict__ mxkey,
                                              float* __restrict__ hpsum) {
    __shared__ float tile[64][65];
    int b = blockIdx.x, t = threadIdx.x;
    if (b < 4096) {
        int lane = t & 63;
        #pragma unroll
        for (int i = 0; i < 16; i++) {
            int tid = ((b * 16 + i) << 8) + t;
            unsigned long long mask = __ballot(adj[tid] > 0);
            if (lane == 0) {
                int base = tid >> 5;
                adjw[base] = (unsigned)mask;
                adjw[base + 1] = (unsigned)(mask >> 32);
            }
        }
    } else if (b < 4160) {
        int idx = b - 4096;
        int h = idx >> 3;
        int d0 = (idx & 7) * 64;
        #pragma unroll
        for (int kidx = 0; kidx < 4; kidx++) {
            int id = t + 256 * kidx;
            int dd = id >> 4, f4i = (id & 15) * 4;
            float4 v = *(const float4*)(W + ((size_t)(h * DD + d0 + dd)) * FF + f4i);
            tile[dd][f4i] = v.x; tile[dd][f4i + 1] = v.y;
            tile[dd][f4i + 2] = v.z; tile[dd][f4i + 3] = v.w;
        }
        __syncthreads();
        int f = t >> 2, c = (t & 3) * 16;
        union { unsigned short s[16]; uint4 v[2]; } hb, lb;
        #pragma unroll
        for (int q = 0; q < 16; q++) {
            float v = tile[c + q][f];
            unsigned short hi = f2bf(v);
            hb.s[q] = hi;
            lb.s[q] = f2bf(v - bf2f(hi));
        }
        uint4* dh = (uint4*)(wt_hi + ((size_t)h * FF + f) * DD + d0 + c);
        uint4* dl = (uint4*)(wt_lo + ((size_t)h * FF + f) * DD + d0 + c);
        dh[0] = hb.v[0]; dh[1] = hb.v[1];
        dl[0] = lb.v[0]; dl[1] = lb.v[1];
    } else {
        if (t < 16) mxkey[t] = 0u;
        hpsum[t] = 0.f;
        hpsum[t + 256] = 0.f;
    }
}

// ================= Kernel 2: hp GEMM, 3-stage pipelined K-loop ========
__global__ __launch_bounds__(256) void k_hp_mfma(const float* __restrict__ hmat,
                                                 const unsigned short* __restrict__ whi,
                                                 const unsigned short* __restrict__ wlo,
                                                 const float* __restrict__ a,
                                                 unsigned short* __restrict__ hpT_hi,
                                                 float* __restrict__ fs,
                                                 float* __restrict__ fd,
                                                 float* __restrict__ hpsum,
                                                 unsigned* __restrict__ mxkey) {
    __shared__ char smem[4 * 64 * SP * 2];   // 36864 B
    unsigned short* ah = (unsigned short*)smem;
    unsigned short* al = ah + 64 * SP;
    unsigned short* bh = al + 64 * SP;
    unsigned short* bl = bh + 64 * SP;

    int t = threadIdx.x;
    int h = blockIdx.y;
    int n0 = blockIdx.x * 64;
    int lane = t & 63;
    int w = t >> 6;
    int R0 = (w >> 1) * 32, F0 = (w & 1) * 32;
    int am = lane & 15, aq = lane >> 4;
    int sr = t >> 2, sc = (t & 3) * 16;

    const float* gha = hmat + (size_t)(n0 + sr) * DD;
    const unsigned short* gbh = whi + ((size_t)h * FF + sr) * DD;
    const unsigned short* gbl = wlo + ((size_t)h * FF + sr) * DD;

    float4 p0, p1, p2, p3;
    uint4 w0, w1, x0, x1;
    auto gload = [&](int kk) {
        p0 = *(const float4*)(gha + kk + sc);
        p1 = *(const float4*)(gha + kk + sc + 4);
        p2 = *(const float4*)(gha + kk + sc + 8);
        p3 = *(const float4*)(gha + kk + sc + 12);
        const uint4* s2 = (const uint4*)(gbh + kk + sc);
        const uint4* s3 = (const uint4*)(gbl + kk + sc);
        w0 = s2[0]; w1 = s2[1]; x0 = s3[0]; x1 = s3[1];
    };
    auto wstage = [&]() {
        union { unsigned short s[16]; uint4 v[2]; } hb, lb;
        #pragma unroll
        for (int q = 0; q < 16; q++) {
            float v = q < 4 ? f4c(p0, q) : q < 8 ? f4c(p1, q - 4)
                      : q < 12 ? f4c(p2, q - 8) : f4c(p3, q - 12);
            unsigned short hi = f2bf(v);
            hb.s[q] = hi;
            lb.s[q] = f2bf(v - bf2f(hi));
        }
        *(uint4*)(ah + sr * SP + sc) = hb.v[0]; *(uint4*)(ah + sr * SP + sc + 8) = hb.v[1];
        *(uint4*)(al + sr * SP + sc) = lb.v[0]; *(uint4*)(al + sr * SP + sc + 8) = lb.v[1];
        *(uint4*)(bh + sr * SP + sc) = w0; *(uint4*)(bh + sr * SP + sc + 8) = w1;
        *(uint4*)(bl + sr * SP + sc) = x0; *(uint4*)(bl + sr * SP + sc + 8) = x1;
    };

    f32x4 acc[2][2] = {};
    gload(0);
    for (int kk = 0; kk < DD; kk += 64) {
        wstage();
        if (kk + 64 < DD) gload(kk + 64);
        sync_lds();
        #pragma unroll
        for (int k2 = 0; k2 < 2; k2++) {
            int ko = k2 * 32 + aq * 8;
            bf16x8 a0h = *(const bf16x8*)(ah + (R0 + am) * SP + ko);
            bf16x8 a1h = *(const bf16x8*)(ah + (R0 + 16 + am) * SP + ko);
            bf16x8 a0l = *(const bf16x8*)(al + (R0 + am) * SP + ko);
            bf16x8 a1l = *(const bf16x8*)(al + (R0 + 16 + am) * SP + ko);
            bf16x8 b0h = *(const bf16x8*)(bh + (F0 + am) * SP + ko);
            bf16x8 b1h = *(const bf16x8*)(bh + (F0 + 16 + am) * SP + ko);
            bf16x8 b0l = *(const bf16x8*)(bl + (F0 + am) * SP + ko);
            bf16x8 b1l = *(const bf16x8*)(bl + (F0 + 16 + am) * SP + ko);
            acc[0][0] = __builtin_amdgcn_mfma_f32_16x16x32_bf16(a0h, b0h, acc[0][0], 0, 0, 0);
            acc[0][1] = __builtin_amdgcn_mfma_f32_16x16x32_bf16(a0h, b1h, acc[0][1], 0, 0, 0);
            acc[1][0] = __builtin_amdgcn_mfma_f32_16x16x32_bf16(a1h, b0h, acc[1][0], 0, 0, 0);
            acc[1][1] = __builtin_amdgcn_mfma_f32_16x16x32_bf16(a1h, b1h, acc[1][1], 0, 0, 0);
            acc[0][0] = __builtin_amdgcn_mfma_f32_16x16x32_bf16(a0h, b0l, acc[0][0], 0, 0, 0);
            acc[0][1] = __builtin_amdgcn_mfma_f32_16x16x32_bf16(a0h, b1l, acc[0][1], 0, 0, 0);
            acc[1][0] = __builtin_amdgcn_mfma_f32_16x16x32_bf16(a1h, b0l, acc[1][0], 0, 0, 0);
            acc[1][1] = __builtin_amdgcn_mfma_f32_16x16x32_bf16(a1h, b1l, acc[1][1], 0, 0, 0);
            acc[0][0] = __builtin_amdgcn_mfma_f32_16x16x32_bf16(a0l, b0h, acc[0][0], 0, 0, 0);
            acc[0][1] = __builtin_amdgcn_mfma_f32_16x16x32_bf16(a0l, b1h, acc[0][1], 0, 0, 0);
            acc[1][0] = __builtin_amdgcn_mfma_f32_16x16x32_bf16(a1l, b0h, acc[1][0], 0, 0, 0);
            acc[1][1] = __builtin_amdgcn_mfma_f32_16x16x32_bf16(a1l, b1h, acc[1][1], 0, 0, 0);
        }
        sync_lds();
    }

    unsigned* tt = (unsigned*)smem;
    float* rs = (float*)(smem + 17408);
    float* rd = rs + 256;
    float* ash = rd + 256;
    if (t < 128) ash[t] = a[h * 2 * FF + t];
    int col = lane & 15, rbase = (lane >> 4) * 4;
    #pragma unroll
    for (int m16 = 0; m16 < 2; m16++) {
        #pragma unroll
        for (int n16 = 0; n16 < 2; n16++) {
            #pragma unroll
            for (int r = 0; r < 4; r++) {
                int nl = R0 + m16 * 16 + rbase + r;
                int f = F0 + n16 * 16 + col;
                float v = acc[m16][n16][r];
                unsigned short hi = f2bf(v);
                unsigned short lo = f2bf(v - bf2f(hi));
                tt[f * 68 + nl] = (unsigned)hi | ((unsigned)lo << 16);
            }
        }
    }
    __syncthreads();
    {
        int f = t >> 2, c = (t & 3) * 16;
        union { unsigned short s[16]; uint4 v[2]; } hb;
        float csum = 0.f;
        #pragma unroll
        for (int q = 0; q < 16; q++) {
            unsigned u = tt[f * 68 + c + q];
            hb.s[q] = (unsigned short)(u & 0xffffu);
            csum += bf2f((unsigned short)(u & 0xffffu)) + bf2f((unsigned short)(u >> 16));
        }
        uint4* dh = (uint4*)(hpT_hi + ((size_t)h * FF + f) * NN + n0 + c);
        dh[0] = hb.v[0]; dh[1] = hb.v[1];
        csum += __shfl_xor(csum, 1);
        csum += __shfl_xor(csum, 2);
        if ((t & 3) == 0) unsafeAtomicAdd(hpsum + h * FF + f, csum);
    }
    {
        int n = t & 63, g = t >> 6;
        float fsp = 0.f, fdp = 0.f;
        #pragma unroll
        for (int q = 0; q < 16; q++) {
            int f = g * 16 + q;
            unsigned u = tt[f * 68 + n];
            float v = bf2f((unsigned short)(u & 0xffffu)) + bf2f((unsigned short)(u >> 16));
            fsp += v * ash[f];
            fdp += v * ash[64 + f];
        }
        rs[g * 64 + n] = fsp;
        rd[g * 64 + n] = fdp;
    }
    __syncthreads();
    if (t < 64) {
        float fdv = rd[t] + rd[64 + t] + rd[128 + t] + rd[192 + t];
        fs[(size_t)h * NN + n0 + t] = rs[t] + rs[64 + t] + rs[128 + t] + rs[192 + t];
        fd[(size_t)h * NN + n0 + t] = fdv;
        unsigned key = fkey(fdv);
        #pragma unroll
        for (int off = 32; off; off >>= 1) key = max(key, (unsigned)__shfl_xor((int)key, off));
        if (t == 0) atomicMax(mxkey + h, key);
    }
}

// ================= Kernel 3: attention — hybrid + j-split z=2, partial-buffer combine ======
// grid (NN/64, HH, 2), block 256 = 4 waves x 16 q-rows. Each z-block sweeps half the j
// range; non-normalized acc written in FINAL [n][h*F+f] layout to its own buffer
// (z=0 -> accb0, z=1 -> d_out scratch); partial l from ones-MFMA. k_combine merges.
__global__ __launch_bounds__(256) void k_attn(const float* __restrict__ fs,
                                              const float* __restrict__ fd,
                                              const unsigned* __restrict__ mxkey,
                                              const unsigned* __restrict__ adjw,
                                              const unsigned short* __restrict__ hpT_hi,
                                              float* __restrict__ acc0,
                                              float* __restrict__ acc1,
                                              float* __restrict__ lsumbuf) {
    __shared__ unsigned short hbh[2][64 * SP];   // 18432 B

    int t = threadIdx.x;
    int h = blockIdx.y;
    int z = blockIdx.z;
    int wv = t >> 6;
    int q0 = blockIdx.x * 64 + wv * 16;   // wave's 16 q-rows
    int lane = t & 63;
    int am = lane & 15, aq = lane >> 4;
    int sr = t >> 2, sc = (t & 3) * 16;   // hbh staging map (f, j-chunk)
    int jb = z * (NN / 2);

    const float LOG2E = 1.44269504f;
    float mfd = funkey(mxkey[h]);
    float fsr = fs[(size_t)h * NN + q0 + am];
    float sM = fsr + mfd;
    float mr = fmaxf(sM, LRELU_ALPHA * sM) * LOG2E;
    float Ac = __builtin_fmaf(fsr, LOG2E, -mr);
    float Bc = __builtin_fmaf(fsr, LRELU_ALPHA * LOG2E, -mr);

    const unsigned short* gH = hpT_hi + ((size_t)h * FF + sr) * NN + sc + jb;
    const float* pfd = fd + (size_t)h * NN + aq * 8 + jb;
    const unsigned* prow = adjw + (size_t)(q0 + am) * (NN / 32) + (jb >> 5);
    int bsh = aq * 8;

    f32x4 acc[4] = {};
    f32x4 accl = {};
    bf16x8 bones;
    #pragma unroll
    for (int i = 0; i < 8; i++) bones[i] = (short)0x3f80;   // bf16 1.0

    // pipeline registers — all NAMED (no runtime-indexed arrays -> no scratch)
    uint4 H0, H1;                                   // H tile (single set)
    float4 XFa0, XFa1, XFb0, XFb1; uint2 XAw;       // F/adj for even tiles
    float4 YFa0, YFa1, YFb0, YFb1; uint2 YAw;       // F/adj for odd tiles

    auto gloadH = [&](int j0) {
        H0 = *(const uint4*)(gH + j0);
        H1 = *(const uint4*)(gH + j0 + 8);
    };
    auto gloadFX = [&](int j0) {
        XFa0 = *(const float4*)(pfd + j0);
        XFa1 = *(const float4*)(pfd + j0 + 4);
        XFb0 = *(const float4*)(pfd + j0 + 32);
        XFb1 = *(const float4*)(pfd + j0 + 36);
        XAw  = *(const uint2*)(prow + (j0 >> 5));
    };
    auto gloadFY = [&](int j0) {
        YFa0 = *(const float4*)(pfd + j0);
        YFa1 = *(const float4*)(pfd + j0 + 4);
        YFb0 = *(const float4*)(pfd + j0 + 32);
        YFb1 = *(const float4*)(pfd + j0 + 36);
        YAw  = *(const uint2*)(prow + (j0 >> 5));
    };
    auto wstageH = [&](int buf) {
        *(uint4*)(&hbh[buf][sr * SP + sc]) = H0;
        *(uint4*)(&hbh[buf][sr * SP + sc + 8]) = H1;
    };
    auto agen = [&](float4 f0, float4 f1, unsigned word) -> bf16x8 {
        unsigned bits = word >> bsh;
        unsigned eu[8];
        #pragma unroll
        for (int q = 0; q < 2; q++) {
            float4 fdv = q ? f1 : f0;
            #pragma unroll
            for (int b = 0; b < 4; b++) {
                float fdL = f4c(fdv, b) * LOG2E;
                float t1 = Ac + fdL;
                float t2 = __builtin_fmaf(fdL, LRELU_ALPHA, Bc);
                float e = __builtin_amdgcn_exp2f(fmaxf(t1, t2));
                e = ((bits >> (q * 4 + b)) & 1u) ? e : 0.f;
                eu[q * 4 + b] = __float_as_uint(e);
            }
        }
        union { unsigned u[4]; bf16x8 v; } af;
        af.u[0] = __builtin_amdgcn_perm(eu[1], eu[0], 0x07060302);
        af.u[1] = __builtin_amdgcn_perm(eu[3], eu[2], 0x07060302);
        af.u[2] = __builtin_amdgcn_perm(eu[5], eu[4], 0x07060302);
        af.u[3] = __builtin_amdgcn_perm(eu[7], eu[6], 0x07060302);
        return af.v;
    };
    auto mfma_tile = [&](int buf, bf16x8 afA, bf16x8 afB) {
        {
            int ko = aq * 8;
            bf16x8 b0 = *(const bf16x8*)(&hbh[buf][(am) * SP + ko]);
            bf16x8 b1 = *(const bf16x8*)(&hbh[buf][(16 + am) * SP + ko]);
            bf16x8 b2 = *(const bf16x8*)(&hbh[buf][(32 + am) * SP + ko]);
            bf16x8 b3 = *(const bf16x8*)(&hbh[buf][(48 + am) * SP + ko]);
            acc[0] = __builtin_amdgcn_mfma_f32_16x16x32_bf16(afA, b0, acc[0], 0, 0, 0);
            acc[1] = __builtin_amdgcn_mfma_f32_16x16x32_bf16(afA, b1, acc[1], 0, 0, 0);
            acc[2] = __builtin_amdgcn_mfma_f32_16x16x32_bf16(afA, b2, acc[2], 0, 0, 0);
            acc[3] = __builtin_amdgcn_mfma_f32_16x16x32_bf16(afA, b3, acc[3], 0, 0, 0);
            accl   = __builtin_amdgcn_mfma_f32_16x16x32_bf16(afA, bones, accl, 0, 0, 0);
        }
        {
            int ko = 32 + aq * 8;
            bf16x8 b0 = *(const bf16x8*)(&hbh[buf][(am) * SP + ko]);
            bf16x8 b1 = *(const bf16x8*)(&hbh[buf][(16 + am) * SP + ko]);
            bf16x8 b2 = *(const bf16x8*)(&hbh[buf][(32 + am) * SP + ko]);
            bf16x8 b3 = *(const bf16x8*)(&hbh[buf][(48 + am) * SP + ko]);
            acc[0] = __builtin_amdgcn_mfma_f32_16x16x32_bf16(afB, b0, acc[0], 0, 0, 0);
            acc[1] = __builtin_amdgcn_mfma_f32_16x16x32_bf16(afB, b1, acc[1], 0, 0, 0);
            acc[2] = __builtin_amdgcn_mfma_f32_16x16x32_bf16(afB, b2, acc[2], 0, 0, 0);
            acc[3] = __builtin_amdgcn_mfma_f32_16x16x32_bf16(afB, b3, acc[3], 0, 0, 0);
            accl   = __builtin_amdgcn_mfma_f32_16x16x32_bf16(afB, bones, accl, 0, 0, 0);
        }
    };

    const int NIT = NN / 2 / 64;   // 32, even
    gloadH(0); gloadFX(0);
    wstageH(0);                  // tile 0 -> buf0 (waits vmcnt for tile-0 H only)
    gloadH(64); gloadFY(64);     // tile 1 in flight
    sync_lds();
    for (int kk = 0; kk < NIT; kk += 2) {
        // even tile kk: buf0, X regs
        {
            bf16x8 afA = agen(XFa0, XFa1, XAw.x);
            bf16x8 afB = agen(XFb0, XFb1, XAw.y);
            mfma_tile(0, afA, afB);
            wstageH(1);                                     // tile kk+1
            if (kk + 2 < NIT) { gloadH((kk + 2) * 64); gloadFX((kk + 2) * 64); }
            sync_lds();
        }
        // odd tile kk+1: buf1, Y regs
        {
            bf16x8 afA = agen(YFa0, YFa1, YAw.x);
            bf16x8 afB = agen(YFb0, YFb1, YAw.y);
            mfma_tile(1, afA, afB);
            if (kk + 2 < NIT) {
                wstageH(0);                                 // tile kk+2
                if (kk + 3 < NIT) { gloadH((kk + 3) * 64); gloadFY((kk + 3) * 64); }
            }
            sync_lds();
        }
    }

    // Partial l: rows q0+rbase+r; all 16 am-lanes duplicate -> write from am==0 only.
    int rbase = (lane >> 4) * 4;
    if (am == 0) {
        #pragma unroll
        for (int r = 0; r < 4; r++)
            lsumbuf[((size_t)z * HH + h) * NN + q0 + rbase + r] = accl[r];
    }

    // Non-normalized partial acc in final [n][h*F+f] layout.
    float* accb = z == 0 ? acc0 : acc1;
    int col = lane & 15;
    #pragma unroll
    for (int r = 0; r < 4; r++) {
        int row = q0 + rbase + r;
        #pragma unroll
        for (int Fi = 0; Fi < 4; Fi++) {
            int f = Fi * 16 + col;
            accb[((size_t)row * HH + h) * FF + f] = acc[Fi][r];
        }
    }
}

// ================= Kernel 4: combine, normalize, ELU (gid->gid; acc1 aliases outp) ==========
__global__ __launch_bounds__(256) void k_combine(const float* __restrict__ acc0,
                                                 const float* acc1,
                                                 const float* __restrict__ lsumbuf,
                                                 const float* __restrict__ hpsum,
                                                 float* outp) {
    int gid = blockIdx.x * 256 + threadIdx.x;    // float4 units over [n][h][f]
    int n = gid >> 7;
    int rem = gid & 127;
    int h = rem >> 4, f4 = (rem & 15) * 4;
    float4 v0 = ((const float4*)acc0)[gid];
    float4 v1 = ((const float4*)acc1)[gid];
    float l = lsumbuf[(size_t)h * NN + n] + lsumbuf[((size_t)HH + h) * NN + n];
    float4 o;
    const float invN = 1.0f / NN;
    #pragma unroll
    for (int c = 0; c < 4; c++) {
        float v;
        if (l > 0.f) v = (f4c(v0, c) + f4c(v1, c)) / l;
        else         v = hpsum[h * FF + f4 + c] * invN;
        f4s(o, c, v > 0.f ? v : __expf(v) - 1.f);
    }
    ((float4*)outp)[gid] = o;
}

extern "C" void kernel_launch(void* const* d_in, const int* in_sizes, int n_in,
                              void* d_out, int out_size, void* d_ws, size_t ws_size,
                              hipStream_t stream) {
    const float* hmat = (const float*)d_in[0];
    const int*   adj  = (const int*)d_in[1];
    const float* W    = (const float*)d_in[2];
    const float* a    = (const float*)d_in[3];
    float* out = (float*)d_out;

    char* ws = (char*)d_ws;
    unsigned short* hpT_hi = (unsigned short*)(ws);                 // 4 MB
    unsigned*       adjw   = (unsigned*)(ws + (4u << 20));          // 2 MB
    unsigned short* wt_hi  = (unsigned short*)(ws + (6u << 20));    // 512 KB
    unsigned short* wt_lo  = (unsigned short*)(ws + (6u << 20) + (512u << 10));
    float* fs    = (float*)(ws + (7u << 20));                       // 128 KB
    float* fd    = (float*)(ws + (7u << 20) + (128u << 10));        // 128 KB
    unsigned* mxkey = (unsigned*)(ws + (7u << 20) + (256u << 10));  // 64 B
    float* hpsum = (float*)(mxkey + 16);                            // 2 KB
    float* lsumbuf = hpsum + 512;                                   // 256 KB
    float* accb0 = (float*)(ws + (8u << 20));                       // 8 MB
    float* accb1 = out;                                             // d_out as z=1 scratch

    k_prep   <<<dim3(4161),            256, 0, stream>>>(adj, W, adjw, wt_hi, wt_lo,
                                                         mxkey, hpsum);
    k_hp_mfma<<<dim3(64, 8),           256, 0, stream>>>(hmat, wt_hi, wt_lo, a,
                                                         hpT_hi, fs, fd, hpsum, mxkey);
    k_attn   <<<dim3(NN / 64, HH, 2),  256, 0, stream>>>(fs, fd, mxkey, adjw,
                                                         hpT_hi, accb0, accb1, lsumbuf);
    k_combine<<<dim3(HH * NN * FF / 4 / 256), 256, 0, stream>>>(accb0, accb1, lsumbuf,
                                                                hpsum, out);
}